// Round 14
// baseline (2298.316 us; speedup 1.0000x reference)
//
#include <hip/hip_runtime.h>
#include <hip/hip_fp16.h>
#include <math.h>

// Problem constants
#define NB 2048      // batch
#define ND 1024      // dim
#define EPS 0.05f
#define NITER 100
#define SBLK 256     // sinkhorn blocks x 256 threads; 8 rows/block, full chip

typedef float f32x4 __attribute__((ext_vector_type(4)));
typedef unsigned u32x4 __attribute__((ext_vector_type(4)));
typedef unsigned u32x2 __attribute__((ext_vector_type(2)));
typedef short s16x8 __attribute__((ext_vector_type(8)));
typedef unsigned short u16x4 __attribute__((ext_vector_type(4)));
union Uh { f32x4 f; __half2 h[4]; };

// ---------------- f32 -> bf16 round-to-nearest-even (bit trick) ----------------
__device__ __forceinline__ unsigned short f2bf(float x) {
    unsigned uu = __float_as_uint(x);
    return (unsigned short)((uu + 0x7FFFu + ((uu >> 16) & 1u)) >> 16);
}

// ---------------- prep: w = nan_to_num(diag(L)), init packed u/v words, zero max ----------------
// uP/vP: 2048 x u32, word = (epoch << 16) | bf16bits(value). init: epoch 0, value 1/NB.
// bf16(1/2048) = bf16(2^-11) = 0x3A00 exactly.
__global__ void prep_k(const float* __restrict__ L, float* __restrict__ w,
                       unsigned* __restrict__ uP, unsigned* __restrict__ vP,
                       unsigned* __restrict__ maxbits) {
    int gtid = blockIdx.x * 256 + threadIdx.x;   // 0..2047
    if (gtid < ND) {
        float x = L[(size_t)gtid * (ND + 1)];
        if (x != x) x = 0.f;
        else if (fabsf(x) == INFINITY) x = (x > 0.f) ? 3.4028235e38f : -3.4028235e38f;
        w[gtid] = x;
    }
    uP[gtid] = 0x3A00u;
    vP[gtid] = 0x3A00u;
    if (gtid == 0) *maxbits = 0u;
}

// ---------------- per-row weighted squared norms ----------------
__global__ __launch_bounds__(256) void rows_k(const float* __restrict__ audio,
                                              const float* __restrict__ text,
                                              const float* __restrict__ w,
                                              float* __restrict__ aw, float* __restrict__ tw) {
    int r = blockIdx.x, tid = threadIdx.x;
    float4 wv = *(const float4*)&w[tid * 4];
    float4 a4 = *(const float4*)&audio[(size_t)r * ND + tid * 4];
    float4 t4 = *(const float4*)&text[(size_t)r * ND + tid * 4];
    float sa = a4.x * a4.x * wv.x + a4.y * a4.y * wv.y + a4.z * a4.z * wv.z + a4.w * a4.w * wv.w;
    float st = t4.x * t4.x * wv.x + t4.y * t4.y * wv.y + t4.z * t4.z * wv.z + t4.w * t4.w * wv.w;
    #pragma unroll
    for (int off = 32; off; off >>= 1) {
        sa += __shfl_down(sa, off, 64);
        st += __shfl_down(st, off, 64);
    }
    __shared__ float red[8];
    if ((tid & 63) == 0) { red[tid >> 6] = sa; red[4 + (tid >> 6)] = st; }
    __syncthreads();
    if (tid == 0) {
        aw[r] = red[0] + red[1] + red[2] + red[3];
        tw[r] = red[4] + red[5] + red[6] + red[7];
    }
}

// ---------------- bf16 MFMA GEMM -> M_dist (f16, row + col major) + global max ----------------
__global__ __launch_bounds__(256) void gemm_mdist(
        const float* __restrict__ Tm, const float* __restrict__ Am,
        const float* __restrict__ wd, const float* __restrict__ tw, const float* __restrict__ aw,
        __half* __restrict__ Md, __half* __restrict__ MdT,
        float* __restrict__ diagMd, unsigned* __restrict__ maxbits) {
    __shared__ __align__(16) unsigned char smem[38912];
    float* wl = (float*)(smem + 34816);
    const int t = threadIdx.x;
    const int row0 = blockIdx.y * 128, col0 = blockIdx.x * 128;
    *(f32x4*)&wl[t * 4] = *(const f32x4*)&wd[t * 4];
    const int wv = t >> 6;                 // wave 0..3
    const int wr = wv >> 1, wc = wv & 1;   // 2x2 wave grid, 64x64 out each
    const int l = t & 63, lr = l & 15, kg = l >> 4;
    const int trow = t >> 4, tk4 = t & 15;
    const int px = (((tk4 >> 1) ^ (trow & 7)) << 4) + ((tk4 & 1) << 3);
    f32x4 acc[4][4];
    #pragma unroll
    for (int m = 0; m < 4; ++m)
        #pragma unroll
        for (int n = 0; n < 4; ++n) acc[m][n] = (f32x4){0.f, 0.f, 0.f, 0.f};
    __syncthreads();
    const float* tp = Tm + (size_t)(row0 + trow) * ND + tk4 * 4;
    const float* ap = Am + (size_t)(col0 + trow) * ND + tk4 * 4;
    for (int k0 = 0; k0 < ND; k0 += 64) {
        f32x4 wv4 = *(const f32x4*)&wl[k0 + tk4 * 4];
        __syncthreads();
        #pragma unroll
        for (int s = 0; s < 8; ++s) {
            f32x4 tv = *(const f32x4*)(tp + (size_t)(s * 16) * ND + k0);
            f32x4 av = *(const f32x4*)(ap + (size_t)(s * 16) * ND + k0);
            tv *= wv4;
            u16x4 tb, ab;
            tb[0] = f2bf(tv[0]); tb[1] = f2bf(tv[1]); tb[2] = f2bf(tv[2]); tb[3] = f2bf(tv[3]);
            ab[0] = f2bf(av[0]); ab[1] = f2bf(av[1]); ab[2] = f2bf(av[2]); ab[3] = f2bf(av[3]);
            const int rb = (s * 16 + trow) * 128 + px;
            *(u16x4*)(smem + rb) = tb;
            *(u16x4*)(smem + 16384 + rb) = ab;
        }
        __syncthreads();
        #pragma unroll
        for (int kk = 0; kk < 2; ++kk) {
            const int sl = (((kk << 2) + kg) ^ (lr & 7)) << 4;
            s16x8 af[4], bfr[4];
            #pragma unroll
            for (int m = 0; m < 4; ++m)
                af[m] = *(const s16x8*)(smem + (wr * 64 + m * 16 + lr) * 128 + sl);
            #pragma unroll
            for (int n = 0; n < 4; ++n)
                bfr[n] = *(const s16x8*)(smem + 16384 + (wc * 64 + n * 16 + lr) * 128 + sl);
            #pragma unroll
            for (int m = 0; m < 4; ++m)
                #pragma unroll
                for (int n = 0; n < 4; ++n)
                    acc[m][n] = __builtin_amdgcn_mfma_f32_16x16x32_bf16(af[m], bfr[n], acc[m][n], 0, 0, 0);
        }
    }
    __syncthreads();
    unsigned short* tr = (unsigned short*)smem;
    unsigned short* mdp = (unsigned short*)Md;
    float lmax = 0.f;
    #pragma unroll
    for (int m = 0; m < 4; ++m) {
        #pragma unroll
        for (int r = 0; r < 4; ++r) {
            const int li = wr * 64 + m * 16 + kg * 4 + r;
            const int i = row0 + li;
            const float twi = tw[i];
            #pragma unroll
            for (int n = 0; n < 4; ++n) {
                const int lj = wc * 64 + n * 16 + lr;
                const int j = col0 + lj;
                float md = twi + aw[j] - 2.0f * acc[m][n][r];
                md = sqrtf(fmaxf(md, 0.f));
                lmax = fmaxf(lmax, md);
                const unsigned short hb = __half_as_ushort(__float2half(md));
                mdp[(size_t)i * NB + j] = hb;
                tr[lj * 136 + li] = hb;
                if (i == j) diagMd[i] = md;
            }
        }
    }
    __syncthreads();
    {
        const int jj = t >> 1, ih = (t & 1) * 64;
        unsigned short* dst = (unsigned short*)MdT + (size_t)(col0 + jj) * NB + row0 + ih;
        #pragma unroll
        for (int x = 0; x < 8; ++x)
            *(s16x8*)(dst + x * 8) = *(const s16x8*)&tr[jj * 136 + ih + x * 8];
    }
    #pragma unroll
    for (int off = 32; off; off >>= 1) lmax = fmaxf(lmax, __shfl_down(lmax, off, 64));
    float* red = (float*)(smem + 34816);
    if (l == 0) red[t >> 6] = lmax;
    __syncthreads();
    if (t == 0) {
        float m2 = fmaxf(fmaxf(red[0], red[1]), fmaxf(red[2], red[3]));
        atomicMax(maxbits, __float_as_uint(m2));
    }
}

// 8 x dwordx4 LLC-coherent load of one wave's full 8KB vector slice (lane l: words l*32..l*32+31)
#define LOAD8(p0) asm volatile( \
        "global_load_dwordx4 %0, %8, off sc0 sc1\n\t" \
        "global_load_dwordx4 %1, %8, off offset:16 sc0 sc1\n\t" \
        "global_load_dwordx4 %2, %8, off offset:32 sc0 sc1\n\t" \
        "global_load_dwordx4 %3, %8, off offset:48 sc0 sc1\n\t" \
        "global_load_dwordx4 %4, %8, off offset:64 sc0 sc1\n\t" \
        "global_load_dwordx4 %5, %8, off offset:80 sc0 sc1\n\t" \
        "global_load_dwordx4 %6, %8, off offset:96 sc0 sc1\n\t" \
        "global_load_dwordx4 %7, %8, off offset:112 sc0 sc1\n\t" \
        "s_waitcnt vmcnt(0)" \
        : "=&v"(d0), "=&v"(d1), "=&v"(d2), "=&v"(d3), \
          "=&v"(d4), "=&v"(d5), "=&v"(d6), "=&v"(d7) \
        : "v"(p0) : "memory")

#define CHK4(dd) ((dd[0] >= phw) && (dd[1] >= phw) && (dd[2] >= phw) && (dd[3] >= phw))

// ---------------- per-wave half-step on epoch-tagged data: poll = data load ----------------
// words: (epoch<<16) | bf16(value); decode = as_float(word<<16). Wait epochs >= ph,
// dot with kreg, store 2 output words tagged epout. No flags, barriers, or drains.
__device__ __forceinline__ void half_step_pair(const f32x4 (&kreg)[2][8],
                                               const unsigned* __restrict__ xin,
                                               unsigned* __restrict__ xout,
                                               int row0, float ab, int l,
                                               unsigned ph, unsigned epout) {
    const unsigned phw = ph << 16;
    const unsigned* p0 = xin + (l << 5);
    u32x4 d0, d1, d2, d3, d4, d5, d6, d7;
    LOAD8(p0);
    bool ok = CHK4(d0) && CHK4(d1) && CHK4(d2) && CHK4(d3) &&
              CHK4(d4) && CHK4(d5) && CHK4(d6) && CHK4(d7);
    while (!__all(ok)) {
        __builtin_amdgcn_s_sleep(1);
        if (!ok) {                      // exec-masked: only stale lanes re-load
            LOAD8(p0);
            ok = CHK4(d0) && CHK4(d1) && CHK4(d2) && CHK4(d3) &&
                 CHK4(d4) && CHK4(d5) && CHK4(d6) && CHK4(d7);
        }
    }
    const u32x4 dd[8] = {d0, d1, d2, d3, d4, d5, d6, d7};
    float acc0 = 0.f, acc1 = 0.f;
    #pragma unroll
    for (int j = 0; j < 8; ++j) {
        #pragma unroll
        for (int k = 0; k < 4; ++k) {
            float xv = __uint_as_float(dd[j][k] << 16);   // bf16 decode: one shift
            acc0 = fmaf(kreg[0][j][k], xv, acc0);
            acc1 = fmaf(kreg[1][j][k], xv, acc1);
        }
    }
    #pragma unroll
    for (int off = 32; off; off >>= 1) {
        acc0 += __shfl_down(acc0, off, 64);
        acc1 += __shfl_down(acc1, off, 64);
    }
    if (l == 0) {
        const unsigned tag = epout << 16;
        u32x2 o;
        o[0] = tag | (unsigned)f2bf(ab / acc0);
        o[1] = tag | (unsigned)f2bf(ab / acc1);
        asm volatile("global_store_dwordx2 %1, %0, off sc0 sc1"
                     :: "v"(o), "v"(xout + row0) : "memory");
    }
}

// ---------------- persistent Sinkhorn: 100 x { v = b/(K^T u); u = a/(K v) } ----------------
// 256 blocks x 4 waves x 2 rows. K = exp(-md/(mx*eps)) built once into f32 regs.
// Sync: self-announcing (epoch, bf16-value) words — zero barriers, flags, atomics, LDS.
// bf16 (not f16!) because true v reaches ~2.4e5 (f16 overflow caused R13's NaN).
__global__ __launch_bounds__(256, 1) void sinkhorn_k(
        const __half* __restrict__ Mdr, const __half* __restrict__ Mdc,
        unsigned* __restrict__ uP, unsigned* __restrict__ vP,
        const unsigned* __restrict__ maxbits) {
    const int tid = threadIdx.x, bid = blockIdx.x;
    const int w = tid >> 6, l = tid & 63;
    const int row0 = (bid << 3) + (w << 1);    // 8 rows/block, 2 rows/wave
    const float ab = 1.0f / NB;
    const float mx = __uint_as_float(*maxbits);
    const float cc = -1.0f / (mx * EPS);
    // ---- one-time K build: 2 rows x 32 contiguous cols per matrix per thread ----
    f32x4 kc[2][8], kr[2][8];
    #pragma unroll
    for (int r = 0; r < 2; ++r) {
        const __half* pc = Mdc + (size_t)(row0 + r) * NB + (l << 5);
        const __half* pr = Mdr + (size_t)(row0 + r) * NB + (l << 5);
        #pragma unroll
        for (int q = 0; q < 4; ++q) {
            Uh a; a.f = *(const f32x4*)(pc + (q << 3));
            Uh b; b.f = *(const f32x4*)(pr + (q << 3));
            #pragma unroll
            for (int h = 0; h < 4; ++h) {
                float2 fa = __half22float2(a.h[h]);
                float2 fb = __half22float2(b.h[h]);
                kc[r][2 * q + (h >> 1)][(h & 1) * 2]     = __expf(fa.x * cc);
                kc[r][2 * q + (h >> 1)][(h & 1) * 2 + 1] = __expf(fa.y * cc);
                kr[r][2 * q + (h >> 1)][(h & 1) * 2]     = __expf(fb.x * cc);
                kr[r][2 * q + (h >> 1)][(h & 1) * 2 + 1] = __expf(fb.y * cc);
            }
        }
    }
    for (unsigned it = 0; it < NITER; ++it) {
        // v-step: consumes u@it, produces v@it+1
        half_step_pair(kc, uP, vP, row0, ab, l, it, it + 1);
        // u-step: consumes v@it+1, produces u@it+1
        half_step_pair(kr, vP, uP, row0, ab, l, it + 1, it + 1);
    }
}

// ---------------- loss: -(1/B) * sum_i [log u_i + log v_i + log K_ii] ----------------
__global__ void loss_k(const unsigned* __restrict__ uP, const unsigned* __restrict__ vP,
                       const float* __restrict__ diagMd, const unsigned* __restrict__ maxbits,
                       float* __restrict__ out) {
    int tid = threadIdx.x;
    float mx = __uint_as_float(*maxbits);
    float cc = 1.0f / (mx * EPS);
    double s = 0.0;
    for (int i = tid; i < NB; i += 256) {
        float ui = __uint_as_float(uP[i] << 16);
        float vi = __uint_as_float(vP[i] << 16);
        s += (double)(logf(ui) + logf(vi) - diagMd[i] * cc);
    }
    #pragma unroll
    for (int off = 32; off; off >>= 1) s += __shfl_down(s, off, 64);
    __shared__ double red[4];
    if ((tid & 63) == 0) red[tid >> 6] = s;
    __syncthreads();
    if (tid == 0)
        out[0] = (float)(-(red[0] + red[1] + red[2] + red[3]) / (double)NB);
}

// ---------------- launch ----------------
extern "C" void kernel_launch(void* const* d_in, const int* in_sizes, int n_in,
                              void* d_out, int out_size, void* d_ws, size_t ws_size,
                              hipStream_t stream) {
    const float* audio = (const float*)d_in[0];
    const float* text  = (const float*)d_in[1];
    const float* L     = (const float*)d_in[2];
    char* ws = (char*)d_ws;
    float*    w       = (float*)(ws + 0);
    float*    aw      = (float*)(ws + 4096);
    float*    tw      = (float*)(ws + 12288);
    unsigned* uP      = (unsigned*)(ws + 20480);   // 2048 x packed (epoch,bf16) = 8KB
    unsigned* vP      = (unsigned*)(ws + 28672);   // 8KB
    float*    diagMd  = (float*)(ws + 36864);
    unsigned* maxbits = (unsigned*)(ws + 45056);
    __half*   Md      = (__half*)(ws + 65536);                          // md row-major
    __half*   MdT     = (__half*)(ws + 65536 + (size_t)NB * NB * 2);    // md col-major

    prep_k<<<8, 256, 0, stream>>>(L, w, uP, vP, maxbits);
    rows_k<<<NB, 256, 0, stream>>>(audio, text, w, aw, tw);
    gemm_mdist<<<dim3(16, 16), 256, 0, stream>>>(text, audio, w, tw, aw, Md, MdT, diagMd, maxbits);
    sinkhorn_k<<<SBLK, 256, 0, stream>>>(Md, MdT, uP, vP, maxbits);
    loss_k<<<1, 256, 0, stream>>>(uP, vP, diagMd, maxbits, (float*)d_out);
}

// Round 15
// 782.878 us; speedup vs baseline: 2.9357x; 2.9357x over previous
//
#include <hip/hip_runtime.h>
#include <hip/hip_fp16.h>
#include <math.h>

// Problem constants
#define NB 2048      // batch
#define ND 1024      // dim
#define EPS 0.05f
#define NITER 100
#define SBLK 256     // sinkhorn blocks x 256 threads; 8 rows/block, full chip

typedef float f32x4 __attribute__((ext_vector_type(4)));
typedef unsigned u32x4 __attribute__((ext_vector_type(4)));
typedef short s16x8 __attribute__((ext_vector_type(8)));
typedef unsigned short u16x4 __attribute__((ext_vector_type(4)));
union Uh { f32x4 f; __half2 h[4]; };

// ---------------- f32 -> bf16 round-to-nearest-even (bit trick) ----------------
__device__ __forceinline__ unsigned f2bf(float x) {
    unsigned uu = __float_as_uint(x);
    return (uu + 0x7FFFu + ((uu >> 16) & 1u)) >> 16;
}

// ---------------- prep: w = nan_to_num(diag(L)), init u/v (bf16 pairs), zero flags+max ----------------
// uP/vP: 1024 x u32, word w = bf16(x[2w]) | bf16(x[2w+1])<<16. bf16(1/2048)=0x3A00.
__global__ void prep_k(const float* __restrict__ L, float* __restrict__ w,
                       unsigned* __restrict__ uP, unsigned* __restrict__ vP,
                       unsigned* __restrict__ maxbits, unsigned* __restrict__ flags) {
    int gtid = blockIdx.x * 256 + threadIdx.x;   // 0..2047
    if (gtid < ND) {
        float x = L[(size_t)gtid * (ND + 1)];
        if (x != x) x = 0.f;
        else if (fabsf(x) == INFINITY) x = (x > 0.f) ? 3.4028235e38f : -3.4028235e38f;
        w[gtid] = x;
    }
    if (gtid < 1024) { uP[gtid] = 0x3A003A00u; vP[gtid] = 0x3A003A00u; }
    if (gtid == 0) *maxbits = 0u;
    if (gtid < 1024) flags[gtid] = 0u;   // 256 flags x 16B
}

// ---------------- per-row weighted squared norms ----------------
__global__ __launch_bounds__(256) void rows_k(const float* __restrict__ audio,
                                              const float* __restrict__ text,
                                              const float* __restrict__ w,
                                              float* __restrict__ aw, float* __restrict__ tw) {
    int r = blockIdx.x, tid = threadIdx.x;
    float4 wv = *(const float4*)&w[tid * 4];
    float4 a4 = *(const float4*)&audio[(size_t)r * ND + tid * 4];
    float4 t4 = *(const float4*)&text[(size_t)r * ND + tid * 4];
    float sa = a4.x * a4.x * wv.x + a4.y * a4.y * wv.y + a4.z * a4.z * wv.z + a4.w * a4.w * wv.w;
    float st = t4.x * t4.x * wv.x + t4.y * t4.y * wv.y + t4.z * t4.z * wv.z + t4.w * t4.w * wv.w;
    #pragma unroll
    for (int off = 32; off; off >>= 1) {
        sa += __shfl_down(sa, off, 64);
        st += __shfl_down(st, off, 64);
    }
    __shared__ float red[8];
    if ((tid & 63) == 0) { red[tid >> 6] = sa; red[4 + (tid >> 6)] = st; }
    __syncthreads();
    if (tid == 0) {
        aw[r] = red[0] + red[1] + red[2] + red[3];
        tw[r] = red[4] + red[5] + red[6] + red[7];
    }
}

// ---------------- bf16 MFMA GEMM -> M_dist (f16, row + col major) + global max ----------------
__global__ __launch_bounds__(256) void gemm_mdist(
        const float* __restrict__ Tm, const float* __restrict__ Am,
        const float* __restrict__ wd, const float* __restrict__ tw, const float* __restrict__ aw,
        __half* __restrict__ Md, __half* __restrict__ MdT,
        float* __restrict__ diagMd, unsigned* __restrict__ maxbits) {
    __shared__ __align__(16) unsigned char smem[38912];
    float* wl = (float*)(smem + 34816);
    const int t = threadIdx.x;
    const int row0 = blockIdx.y * 128, col0 = blockIdx.x * 128;
    *(f32x4*)&wl[t * 4] = *(const f32x4*)&wd[t * 4];
    const int wv = t >> 6;                 // wave 0..3
    const int wr = wv >> 1, wc = wv & 1;   // 2x2 wave grid, 64x64 out each
    const int l = t & 63, lr = l & 15, kg = l >> 4;
    const int trow = t >> 4, tk4 = t & 15;
    const int px = (((tk4 >> 1) ^ (trow & 7)) << 4) + ((tk4 & 1) << 3);
    f32x4 acc[4][4];
    #pragma unroll
    for (int m = 0; m < 4; ++m)
        #pragma unroll
        for (int n = 0; n < 4; ++n) acc[m][n] = (f32x4){0.f, 0.f, 0.f, 0.f};
    __syncthreads();
    const float* tp = Tm + (size_t)(row0 + trow) * ND + tk4 * 4;
    const float* ap = Am + (size_t)(col0 + trow) * ND + tk4 * 4;
    for (int k0 = 0; k0 < ND; k0 += 64) {
        f32x4 wv4 = *(const f32x4*)&wl[k0 + tk4 * 4];
        __syncthreads();
        #pragma unroll
        for (int s = 0; s < 8; ++s) {
            f32x4 tv = *(const f32x4*)(tp + (size_t)(s * 16) * ND + k0);
            f32x4 av = *(const f32x4*)(ap + (size_t)(s * 16) * ND + k0);
            tv *= wv4;
            u16x4 tb, ab;
            tb[0] = (unsigned short)f2bf(tv[0]); tb[1] = (unsigned short)f2bf(tv[1]);
            tb[2] = (unsigned short)f2bf(tv[2]); tb[3] = (unsigned short)f2bf(tv[3]);
            ab[0] = (unsigned short)f2bf(av[0]); ab[1] = (unsigned short)f2bf(av[1]);
            ab[2] = (unsigned short)f2bf(av[2]); ab[3] = (unsigned short)f2bf(av[3]);
            const int rb = (s * 16 + trow) * 128 + px;
            *(u16x4*)(smem + rb) = tb;
            *(u16x4*)(smem + 16384 + rb) = ab;
        }
        __syncthreads();
        #pragma unroll
        for (int kk = 0; kk < 2; ++kk) {
            const int sl = (((kk << 2) + kg) ^ (lr & 7)) << 4;
            s16x8 af[4], bfr[4];
            #pragma unroll
            for (int m = 0; m < 4; ++m)
                af[m] = *(const s16x8*)(smem + (wr * 64 + m * 16 + lr) * 128 + sl);
            #pragma unroll
            for (int n = 0; n < 4; ++n)
                bfr[n] = *(const s16x8*)(smem + 16384 + (wc * 64 + n * 16 + lr) * 128 + sl);
            #pragma unroll
            for (int m = 0; m < 4; ++m)
                #pragma unroll
                for (int n = 0; n < 4; ++n)
                    acc[m][n] = __builtin_amdgcn_mfma_f32_16x16x32_bf16(af[m], bfr[n], acc[m][n], 0, 0, 0);
        }
    }
    __syncthreads();
    unsigned short* tr = (unsigned short*)smem;
    unsigned short* mdp = (unsigned short*)Md;
    float lmax = 0.f;
    #pragma unroll
    for (int m = 0; m < 4; ++m) {
        #pragma unroll
        for (int r = 0; r < 4; ++r) {
            const int li = wr * 64 + m * 16 + kg * 4 + r;
            const int i = row0 + li;
            const float twi = tw[i];
            #pragma unroll
            for (int n = 0; n < 4; ++n) {
                const int lj = wc * 64 + n * 16 + lr;
                const int j = col0 + lj;
                float md = twi + aw[j] - 2.0f * acc[m][n][r];
                md = sqrtf(fmaxf(md, 0.f));
                lmax = fmaxf(lmax, md);
                const unsigned short hb = __half_as_ushort(__float2half(md));
                mdp[(size_t)i * NB + j] = hb;
                tr[lj * 136 + li] = hb;
                if (i == j) diagMd[i] = md;
            }
        }
    }
    __syncthreads();
    {
        const int jj = t >> 1, ih = (t & 1) * 64;
        unsigned short* dst = (unsigned short*)MdT + (size_t)(col0 + jj) * NB + row0 + ih;
        #pragma unroll
        for (int x = 0; x < 8; ++x)
            *(s16x8*)(dst + x * 8) = *(const s16x8*)&tr[jj * 136 + ih + x * 8];
    }
    #pragma unroll
    for (int off = 32; off; off >>= 1) lmax = fmaxf(lmax, __shfl_down(lmax, off, 64));
    float* red = (float*)(smem + 34816);
    if (l == 0) red[t >> 6] = lmax;
    __syncthreads();
    if (t == 0) {
        float m2 = fmaxf(fmaxf(red[0], red[1]), fmaxf(red[2], red[3]));
        atomicMax(maxbits, __float_as_uint(m2));
    }
}

// ---------------- store-broadcast barrier: 256 flags (16B apart), no RMW anywhere ----------------
// ALL waves poll: lane l loads flags l, l+64, l+128, l+192; all >= ph -> done.  [R12-proven]
__device__ __forceinline__ void wait_phase(const unsigned* __restrict__ flags, int l,
                                           unsigned ph) {
    const unsigned* p = flags + (l << 2);
    for (;;) {
        unsigned f0, f1, f2, f3;
        asm volatile("global_load_dword %0, %4, off sc0 sc1\n\t"
                     "global_load_dword %1, %5, off sc0 sc1\n\t"
                     "global_load_dword %2, %6, off sc0 sc1\n\t"
                     "global_load_dword %3, %7, off sc0 sc1\n\t"
                     "s_waitcnt vmcnt(0)"
                     : "=&v"(f0), "=&v"(f1), "=&v"(f2), "=&v"(f3)
                     : "v"(p), "v"(p + 256), "v"(p + 512), "v"(p + 768) : "memory");
        if (__all((f0 >= ph) && (f1 >= ph) && (f2 >= ph) && (f3 >= ph))) break;
        __builtin_amdgcn_s_sleep(1);
    }
}

// ---------------- per-wave half-step: bf16 data load (4KB/wave) -> dot with Kreg -> 4B store ----------------
// Lane l owns bf16 cols l*32..l*32+31 = 16 u32 words = 4 dwordx4.
__device__ __forceinline__ void half_step_reg(const f32x4 (&kreg)[2][8],
                                              const unsigned* __restrict__ xin,
                                              unsigned* __restrict__ xout,
                                              int row0, float ab, int l) {
    const unsigned* p0 = xin + (l << 4);
    u32x4 d0, d1, d2, d3;
    asm volatile("global_load_dwordx4 %0, %4, off sc0 sc1\n\t"
                 "global_load_dwordx4 %1, %4, off offset:16 sc0 sc1\n\t"
                 "global_load_dwordx4 %2, %4, off offset:32 sc0 sc1\n\t"
                 "global_load_dwordx4 %3, %4, off offset:48 sc0 sc1\n\t"
                 "s_waitcnt vmcnt(0)"
                 : "=&v"(d0), "=&v"(d1), "=&v"(d2), "=&v"(d3)
                 : "v"(p0) : "memory");
    const u32x4 dd[4] = {d0, d1, d2, d3};
    float acc0 = 0.f, acc1 = 0.f;
    #pragma unroll
    for (int qq = 0; qq < 4; ++qq) {
        #pragma unroll
        for (int h = 0; h < 4; ++h) {
            const unsigned word = dd[qq][h];
            const float xlo = __uint_as_float(word << 16);          // bf16 decode
            const float xhi = __uint_as_float(word & 0xFFFF0000u);
            const int rg = 2 * qq + (h >> 1), el = (h & 1) * 2;
            acc0 = fmaf(kreg[0][rg][el], xlo, acc0);
            acc0 = fmaf(kreg[0][rg][el + 1], xhi, acc0);
            acc1 = fmaf(kreg[1][rg][el], xlo, acc1);
            acc1 = fmaf(kreg[1][rg][el + 1], xhi, acc1);
        }
    }
    #pragma unroll
    for (int off = 32; off; off >>= 1) {
        acc0 += __shfl_down(acc0, off, 64);
        acc1 += __shfl_down(acc1, off, 64);
    }
    if (l == 0) {
        const unsigned o = f2bf(ab / acc0) | (f2bf(ab / acc1) << 16);
        asm volatile("global_store_dword %1, %0, off sc0 sc1"
                     :: "v"(o), "v"(xout + (row0 >> 1)) : "memory");
    }
    asm volatile("s_waitcnt vmcnt(0)" ::: "memory");   // wave-wide drain before flag
}

// ---------------- persistent Sinkhorn: 100 x { v = b/(K^T u); u = a/(K v) } ----------------
// 256 blocks x 4 waves x 2 rows. K = exp(-md/(mx*eps)) built once into f32 regs.
// u/v as bf16 pairs (range-safe: v reaches ~2.4e5, bf16 has f32 exponent; validated R14).
// Store-only flags + narrow poll (R12-proven); data loaded exactly once per half-step.
__global__ __launch_bounds__(256, 1) void sinkhorn_k(
        const __half* __restrict__ Mdr, const __half* __restrict__ Mdc,
        unsigned* __restrict__ uP, unsigned* __restrict__ vP,
        const unsigned* __restrict__ maxbits, unsigned* __restrict__ flags) {
    const int tid = threadIdx.x, bid = blockIdx.x;
    const int w = tid >> 6, l = tid & 63;
    const int row0 = (bid << 3) + (w << 1);    // 8 rows/block, 2 rows/wave
    const float ab = 1.0f / NB;
    unsigned* myflag = flags + (bid << 2);     // 16B apart
    const float mx = __uint_as_float(*maxbits);
    const float cc = -1.0f / (mx * EPS);
    // ---- one-time K build: 2 rows x 32 contiguous cols per matrix per thread, exp fused ----
    f32x4 kc[2][8], kr[2][8];
    #pragma unroll
    for (int r = 0; r < 2; ++r) {
        const __half* pc = Mdc + (size_t)(row0 + r) * NB + (l << 5);
        const __half* pr = Mdr + (size_t)(row0 + r) * NB + (l << 5);
        #pragma unroll
        for (int q = 0; q < 4; ++q) {
            Uh a; a.f = *(const f32x4*)(pc + (q << 3));
            Uh b; b.f = *(const f32x4*)(pr + (q << 3));
            #pragma unroll
            for (int h = 0; h < 4; ++h) {
                float2 fa = __half22float2(a.h[h]);
                float2 fb = __half22float2(b.h[h]);
                kc[r][2 * q + (h >> 1)][(h & 1) * 2]     = __expf(fa.x * cc);
                kc[r][2 * q + (h >> 1)][(h & 1) * 2 + 1] = __expf(fa.y * cc);
                kr[r][2 * q + (h >> 1)][(h & 1) * 2]     = __expf(fb.x * cc);
                kr[r][2 * q + (h >> 1)][(h & 1) * 2 + 1] = __expf(fb.y * cc);
            }
        }
    }
    for (int it = 0; it < NITER; ++it) {
        // ---- v-step: v = b / (K^T u); needs u@it (phase 2it) ----
        wait_phase(flags, l, 2 * it);
        half_step_reg(kc, uP, vP, row0, ab, l);
        __syncthreads();                       // all waves stored + drained
        if (tid == 0) {
            unsigned ph = 2 * it + 1;
            asm volatile("global_store_dword %1, %0, off sc0 sc1"
                         :: "v"(ph), "v"(myflag) : "memory");
        }
        // ---- u-step: u = a / (K v); needs v@it+1 (phase 2it+1) ----
        wait_phase(flags, l, 2 * it + 1);
        half_step_reg(kr, vP, uP, row0, ab, l);
        __syncthreads();
        if (tid == 0) {
            unsigned ph = 2 * it + 2;
            asm volatile("global_store_dword %1, %0, off sc0 sc1"
                         :: "v"(ph), "v"(myflag) : "memory");
        }
    }
}

// ---------------- loss: -(1/B) * sum_i [log u_i + log v_i + log K_ii] ----------------
__global__ void loss_k(const unsigned* __restrict__ uP, const unsigned* __restrict__ vP,
                       const float* __restrict__ diagMd, const unsigned* __restrict__ maxbits,
                       float* __restrict__ out) {
    int tid = threadIdx.x;
    float mx = __uint_as_float(*maxbits);
    float cc = 1.0f / (mx * EPS);
    double s = 0.0;
    for (int i = tid; i < NB; i += 256) {
        const unsigned wu = uP[i >> 1], wv2 = vP[i >> 1];
        float ui = __uint_as_float((i & 1) ? (wu & 0xFFFF0000u) : (wu << 16));
        float vi = __uint_as_float((i & 1) ? (wv2 & 0xFFFF0000u) : (wv2 << 16));
        s += (double)(logf(ui) + logf(vi) - diagMd[i] * cc);
    }
    #pragma unroll
    for (int off = 32; off; off >>= 1) s += __shfl_down(s, off, 64);
    __shared__ double red[4];
    if ((tid & 63) == 0) red[tid >> 6] = s;
    __syncthreads();
    if (tid == 0)
        out[0] = (float)(-(red[0] + red[1] + red[2] + red[3]) / (double)NB);
}

// ---------------- launch ----------------
extern "C" void kernel_launch(void* const* d_in, const int* in_sizes, int n_in,
                              void* d_out, int out_size, void* d_ws, size_t ws_size,
                              hipStream_t stream) {
    const float* audio = (const float*)d_in[0];
    const float* text  = (const float*)d_in[1];
    const float* L     = (const float*)d_in[2];
    char* ws = (char*)d_ws;
    float*    w       = (float*)(ws + 0);
    float*    aw      = (float*)(ws + 4096);
    float*    tw      = (float*)(ws + 12288);
    unsigned* uP      = (unsigned*)(ws + 20480);   // 1024 x u32 (bf16 pairs) = 4KB
    unsigned* vP      = (unsigned*)(ws + 28672);   // 4KB
    float*    diagMd  = (float*)(ws + 36864);
    unsigned* maxbits = (unsigned*)(ws + 45056);
    unsigned* flags   = (unsigned*)(ws + 45312);   // 256 flags x 16B = 4KB
    __half*   Md      = (__half*)(ws + 65536);                          // md row-major
    __half*   MdT     = (__half*)(ws + 65536 + (size_t)NB * NB * 2);    // md col-major

    prep_k<<<8, 256, 0, stream>>>(L, w, uP, vP, maxbits, flags);
    rows_k<<<NB, 256, 0, stream>>>(audio, text, w, aw, tw);
    gemm_mdist<<<dim3(16, 16), 256, 0, stream>>>(text, audio, w, tw, aw, Md, MdT, diagMd, maxbits);
    sinkhorn_k<<<SBLK, 256, 0, stream>>>(Md, MdT, uP, vP, maxbits, flags);
    loss_k<<<1, 256, 0, stream>>>(uP, vP, diagMd, maxbits, (float*)d_out);
}